// Round 1
// baseline (234.072 us; speedup 1.0000x reference)
//
#include <hip/hip_runtime.h>
#include <math.h>

// Problem constants (reference: N=250000, D=16, L=6, K=64, gamma=0.1)
#define NPOINTS 250000
#define LL 6
#define DD 16
#define KK 64
#define PPT 4        // points per thread (amortizes broadcast LDS reads of mu)
#define TPB 128      // threads per block -> 512 points/block -> 489 blocks

// workspace float layout
#define MU_OFF 0                  // [L*K][D] normalized mu, column-major-per-(l,k)
#define AA_OFF (LL*KK*DD)         // 6144: -10*log2(e)*alpha[l*K+k]
#define WV_OFF (AA_OFF + LL*KK)   // 6528: exp(-ws[l]^2)
#define WS_FLOATS (WV_OFF + LL)   // 6534 floats = 26136 B needed in d_ws

#if __has_builtin(__builtin_amdgcn_exp2f)
#define EXP2F(x) __builtin_amdgcn_exp2f(x)
#else
#define EXP2F(x) exp2f(x)
#endif
#if __has_builtin(__builtin_amdgcn_logf)
#define LOG2F(x) __builtin_amdgcn_logf(x)
#else
#define LOG2F(x) log2f(x)
#endif
#if __has_builtin(__builtin_amdgcn_sqrtf)
#define SQRTF(x) __builtin_amdgcn_sqrtf(x)
#else
#define SQRTF(x) sqrtf(x)
#endif

// -5*log2(e)/ ... : t = log2(e) * (-(0.5*d^2 + alpha)/gamma), gamma=0.1
//   = d^2 * (-5*log2(e)) + alpha * (-10*log2(e))
#define C_D2   (-7.213475204444817f)    // -5 * log2(e)
#define C_AA   (-14.426950408889634f)   // -10 * log2(e)
#define C_GLN2 (0.06931471805599453f)   // gamma * ln(2)  (for gamma*ln(S) = gln2*log2(S))
#define PI_F   (3.14159265358979323846f)

__global__ void prep_kernel(const float* __restrict__ mus,    // [L, D, K]
                            const float* __restrict__ alphas, // [L, K]
                            const float* __restrict__ wsv,    // [L]
                            float* __restrict__ wsbuf) {
  int t = threadIdx.x;
  if (t < LL * KK) {
    int l = t >> 6;
    int k = t & 63;
    const float* colp = mus + l * (DD * KK) + k;  // stride KK over d
    float v[DD];
    float ss = 0.0f;
#pragma unroll
    for (int d = 0; d < DD; ++d) {
      v[d] = colp[d * KK];
      ss = fmaf(v[d], v[d], ss);
    }
    float inv = 1.0f / sqrtf(ss);   // matches jnp.linalg.norm + divide in fp32
    float* o = wsbuf + MU_OFF + t * DD;
#pragma unroll
    for (int d = 0; d < DD; ++d) o[d] = v[d] * inv;
    wsbuf[AA_OFF + t] = C_AA * alphas[t];
  } else if (t < LL * KK + LL) {
    int l = t - LL * KK;
    float w = wsv[l];
    wsbuf[WV_OFF + l] = expf(-w * w);
  }
}

__global__ __launch_bounds__(TPB, 1) void
multiinf_kernel(const float* __restrict__ xs,
                const float* __restrict__ wsbuf,
                float* __restrict__ out) {
  __shared__ float smu[LL * KK * DD];   // [l][k][d], 24576 B
  __shared__ float saa[LL * KK];        // 1536 B
  __shared__ float swv[LL];

  // Stage mu/aa/wv into LDS (coalesced float4 copies)
  {
    const float4* src4 = (const float4*)wsbuf;
    float4* dmu = (float4*)smu;
    for (int i = threadIdx.x; i < (LL * KK * DD) / 4; i += TPB) dmu[i] = src4[i];
    float4* daa = (float4*)saa;
    for (int i = threadIdx.x; i < (LL * KK) / 4; i += TPB) daa[i] = src4[AA_OFF / 4 + i];
    if (threadIdx.x < LL) swv[threadIdx.x] = wsbuf[WV_OFF + threadIdx.x];
  }
  __syncthreads();

  const int base = blockIdx.x * (TPB * PPT) + threadIdx.x;
  const float4* xs4 = (const float4*)xs;

  float xv[PPT][DD];
  bool valid[PPT];
#pragma unroll
  for (int p = 0; p < PPT; ++p) {
    int idx = base + p * TPB;
    valid[p] = (idx < NPOINTS);
    if (valid[p]) {
#pragma unroll
      for (int j = 0; j < 4; ++j) {
        float4 v = xs4[idx * 4 + j];
        xv[p][j * 4 + 0] = v.x;
        xv[p][j * 4 + 1] = v.y;
        xv[p][j * 4 + 2] = v.z;
        xv[p][j * 4 + 3] = v.w;
      }
    } else {
#pragma unroll
      for (int d = 0; d < DD; ++d) xv[p][d] = 0.0f;
    }
  }

  float F[PPT];
#pragma unroll
  for (int p = 0; p < PPT; ++p) F[p] = 0.0f;

  for (int l = 0; l < LL; ++l) {
    const float* col = smu + l * (KK * DD);
    const float* aap = saa + l * KK;
    float S[PPT];
#pragma unroll
    for (int p = 0; p < PPT; ++p) S[p] = 0.0f;

#pragma unroll 2
    for (int k = 0; k < KK; ++k) {
      const float4* c4 = (const float4*)(col + k * DD);
      float4 m0 = c4[0];
      float4 m1 = c4[1];
      float4 m2 = c4[2];
      float4 m3 = c4[3];
      float aa = aap[k];
#pragma unroll
      for (int p = 0; p < PPT; ++p) {
        float acc = xv[p][0] * m0.x;
        acc = fmaf(xv[p][1], m0.y, acc);
        acc = fmaf(xv[p][2], m0.z, acc);
        acc = fmaf(xv[p][3], m0.w, acc);
        acc = fmaf(xv[p][4], m1.x, acc);
        acc = fmaf(xv[p][5], m1.y, acc);
        acc = fmaf(xv[p][6], m1.z, acc);
        acc = fmaf(xv[p][7], m1.w, acc);
        acc = fmaf(xv[p][8], m2.x, acc);
        acc = fmaf(xv[p][9], m2.y, acc);
        acc = fmaf(xv[p][10], m2.z, acc);
        acc = fmaf(xv[p][11], m2.w, acc);
        acc = fmaf(xv[p][12], m3.x, acc);
        acc = fmaf(xv[p][13], m3.y, acc);
        acc = fmaf(xv[p][14], m3.z, acc);
        acc = fmaf(xv[p][15], m3.w, acc);
        // clip exactly like reference: [-1+1e-7, 1-1e-7] (fp32-folded constants)
        float cx = __builtin_amdgcn_fmed3f(acc, -1.0f + 1e-7f, 1.0f - 1e-7f);
        // acos via Hastings: acos(x) = sqrt(1-|x|)*P(|x|); x<0 -> pi - r
        float ax = fabsf(cx);
        float pp = fmaf(ax, -0.0012624911f, 0.0066700901f);
        pp = fmaf(pp, ax, -0.0170881256f);
        pp = fmaf(pp, ax, 0.0308918810f);
        pp = fmaf(pp, ax, -0.0501743046f);
        pp = fmaf(pp, ax, 0.0889789874f);
        pp = fmaf(pp, ax, -0.2145988016f);
        pp = fmaf(pp, ax, 1.5707963050f);
        float r = SQRTF(1.0f - ax) * pp;
        float dist = (cx < 0.0f) ? (PI_F - r) : r;
        // t = log2e * (-(0.5 d^2 + alpha)/gamma) ; alpha pre-scaled into aa
        float t2 = fmaf(dist * dist, C_D2, aa);
        S[p] += EXP2F(t2);
      }
    }
    float wv = swv[l];
    float omw = 1.0f - wv;
#pragma unroll
    for (int p = 0; p < PPT; ++p) {
      float minc = C_GLN2 * LOG2F(S[p]);           // gamma * ln(sum exp)
      F[p] = fmaf(wv, fmaxf(F[p], 0.0f), omw * minc);
    }
  }

  // smooth min(F, 0): 0.1 * ln(exp(-F/0.1) + 1); max arg ~2^85.6, no overflow
#pragma unroll
  for (int p = 0; p < PPT; ++p) {
    int idx = base + p * TPB;
    if (valid[p]) {
      float e = EXP2F(F[p] * C_AA * 1.0f);  // 2^(-10*log2e*F) = exp(-F/0.1)
      out[idx] = C_GLN2 * LOG2F(1.0f + e);
    }
  }
}

extern "C" void kernel_launch(void* const* d_in, const int* in_sizes, int n_in,
                              void* d_out, int out_size, void* d_ws, size_t ws_size,
                              hipStream_t stream) {
  const float* xs = (const float*)d_in[0];     // [N, D]
  const float* mus = (const float*)d_in[1];    // [L, D, K]
  const float* alphas = (const float*)d_in[2]; // [L, K]
  const float* wsv = (const float*)d_in[3];    // [L]
  float* out = (float*)d_out;
  float* wsbuf = (float*)d_ws;                 // needs 26136 B

  prep_kernel<<<1, 512, 0, stream>>>(mus, alphas, wsv, wsbuf);

  const int blocks = (NPOINTS + TPB * PPT - 1) / (TPB * PPT);  // 489
  multiinf_kernel<<<blocks, TPB, 0, stream>>>(xs, wsbuf, out);
}

// Round 2
// 189.768 us; speedup vs baseline: 1.2335x; 1.2335x over previous
//
#include <hip/hip_runtime.h>
#include <math.h>

// Problem constants (reference: N=250000, D=16, L=6, K=64, gamma=0.1)
#define NPOINTS 250000
#define LL 6
#define DD 16
#define KK 64
#define PPT 4        // points per thread (amortizes broadcast LDS reads of mu)
#define TPB 384      // 6 waves: wave w computes layer w for the block's 256 points
#define PTS_PER_BLOCK 256

// workspace float layout
#define MU_OFF 0                  // [L*K][D] normalized mu
#define AA_OFF (LL*KK*DD)         // 6144: -10*log2(e)*alpha[l*K+k]
#define WV_OFF (AA_OFF + LL*KK)   // 6528: exp(-ws[l]^2)
#define WS_FLOATS (WV_OFF + LL)   // 6534 floats = 26136 B needed in d_ws

#if __has_builtin(__builtin_amdgcn_exp2f)
#define EXP2F(x) __builtin_amdgcn_exp2f(x)
#else
#define EXP2F(x) exp2f(x)
#endif
#if __has_builtin(__builtin_amdgcn_logf)
#define LOG2F(x) __builtin_amdgcn_logf(x)
#else
#define LOG2F(x) log2f(x)
#endif
#if __has_builtin(__builtin_amdgcn_sqrtf)
#define SQRTF(x) __builtin_amdgcn_sqrtf(x)
#else
#define SQRTF(x) sqrtf(x)
#endif

#define C_D2   (-7.213475204444817f)    // -5 * log2(e)
#define C_AA   (-14.426950408889634f)   // -10 * log2(e)
#define C_GLN2 (0.06931471805599453f)   // gamma * ln(2)
#define PI_F   (3.14159265358979323846f)

__global__ void prep_kernel(const float* __restrict__ mus,    // [L, D, K]
                            const float* __restrict__ alphas, // [L, K]
                            const float* __restrict__ wsv,    // [L]
                            float* __restrict__ wsbuf) {
  int t = threadIdx.x;
  if (t < LL * KK) {
    int l = t >> 6;
    int k = t & 63;
    const float* colp = mus + l * (DD * KK) + k;  // stride KK over d
    float v[DD];
    float ss = 0.0f;
#pragma unroll
    for (int d = 0; d < DD; ++d) {
      v[d] = colp[d * KK];
      ss = fmaf(v[d], v[d], ss);
    }
    float inv = 1.0f / sqrtf(ss);
    float* o = wsbuf + MU_OFF + t * DD;
#pragma unroll
    for (int d = 0; d < DD; ++d) o[d] = v[d] * inv;
    wsbuf[AA_OFF + t] = C_AA * alphas[t];
  } else if (t < LL * KK + LL) {
    int l = t - LL * KK;
    float w = wsv[l];
    wsbuf[WV_OFF + l] = expf(-w * w);
  }
}

__global__ __launch_bounds__(TPB, 4) void
multiinf_kernel(const float* __restrict__ xs,
                const float* __restrict__ wsbuf,
                float* __restrict__ out) {
  __shared__ float smu[LL * KK * DD];      // 24576 B  [l][k][d]
  __shared__ float saa[LL * KK];           // 1536 B
  __shared__ float swv[LL];                // 24 B
  __shared__ float smc[LL * PTS_PER_BLOCK];// 6144 B   mincosts[l][point-in-block]

  // Stage mu/aa/wv into LDS (coalesced float4 copies, all 384 threads)
  {
    const float4* src4 = (const float4*)wsbuf;
    float4* dmu = (float4*)smu;
    for (int i = threadIdx.x; i < (LL * KK * DD) / 4; i += TPB) dmu[i] = src4[i];
    float4* daa = (float4*)saa;
    for (int i = threadIdx.x; i < (LL * KK) / 4; i += TPB) daa[i] = src4[AA_OFF / 4 + i];
    if (threadIdx.x < LL) swv[threadIdx.x] = wsbuf[WV_OFF + threadIdx.x];
  }
  __syncthreads();

  const int wave = threadIdx.x >> 6;   // 0..5 -> layer index
  const int lane = threadIdx.x & 63;
  const int pbase = blockIdx.x * PTS_PER_BLOCK;
  const float4* xs4 = (const float4*)xs;

  // Each wave loads the SAME 256 points (L1 absorbs the 6x re-read)
  float xv[PPT][DD];
#pragma unroll
  for (int p = 0; p < PPT; ++p) {
    int idx = pbase + p * 64 + lane;
    if (idx < NPOINTS) {
#pragma unroll
      for (int j = 0; j < 4; ++j) {
        float4 v = xs4[idx * 4 + j];
        xv[p][j * 4 + 0] = v.x;
        xv[p][j * 4 + 1] = v.y;
        xv[p][j * 4 + 2] = v.z;
        xv[p][j * 4 + 3] = v.w;
      }
    } else {
#pragma unroll
      for (int d = 0; d < DD; ++d) xv[p][d] = 0.0f;  // finite path: dist=pi/2
    }
  }

  float S[PPT];
#pragma unroll
  for (int p = 0; p < PPT; ++p) S[p] = 0.0f;

  const float* col0 = smu + wave * (KK * DD);
  const float* aap = saa + wave * KK;

#pragma unroll 4
  for (int k = 0; k < KK; ++k) {
    const float4* c4 = (const float4*)(col0 + k * DD);
    float4 m0 = c4[0];
    float4 m1 = c4[1];
    float4 m2 = c4[2];
    float4 m3 = c4[3];
    float aa = aap[k];
#pragma unroll
    for (int p = 0; p < PPT; ++p) {
      float acc = xv[p][0] * m0.x;
      acc = fmaf(xv[p][1], m0.y, acc);
      acc = fmaf(xv[p][2], m0.z, acc);
      acc = fmaf(xv[p][3], m0.w, acc);
      acc = fmaf(xv[p][4], m1.x, acc);
      acc = fmaf(xv[p][5], m1.y, acc);
      acc = fmaf(xv[p][6], m1.z, acc);
      acc = fmaf(xv[p][7], m1.w, acc);
      acc = fmaf(xv[p][8], m2.x, acc);
      acc = fmaf(xv[p][9], m2.y, acc);
      acc = fmaf(xv[p][10], m2.z, acc);
      acc = fmaf(xv[p][11], m2.w, acc);
      acc = fmaf(xv[p][12], m3.x, acc);
      acc = fmaf(xv[p][13], m3.y, acc);
      acc = fmaf(xv[p][14], m3.z, acc);
      acc = fmaf(xv[p][15], m3.w, acc);
      float cx = __builtin_amdgcn_fmed3f(acc, -1.0f + 1e-7f, 1.0f - 1e-7f);
      float ax = fabsf(cx);
      float pp = fmaf(ax, -0.0012624911f, 0.0066700901f);
      pp = fmaf(pp, ax, -0.0170881256f);
      pp = fmaf(pp, ax, 0.0308918810f);
      pp = fmaf(pp, ax, -0.0501743046f);
      pp = fmaf(pp, ax, 0.0889789874f);
      pp = fmaf(pp, ax, -0.2145988016f);
      pp = fmaf(pp, ax, 1.5707963050f);
      float r = SQRTF(1.0f - ax) * pp;
      float dist = (cx < 0.0f) ? (PI_F - r) : r;
      float t2 = fmaf(dist * dist, C_D2, aa);
      S[p] += EXP2F(t2);
    }
  }

  // mincost for this wave's layer -> LDS
  float* smcw = smc + wave * PTS_PER_BLOCK;
#pragma unroll
  for (int p = 0; p < PPT; ++p) {
    smcw[p * 64 + lane] = C_GLN2 * LOG2F(S[p]);
  }
  __syncthreads();

  // Recurrence + smooth-min epilogue: one thread per point (threads 0..255)
  if (threadIdx.x < PTS_PER_BLOCK) {
    int j = threadIdx.x;
    float F = 0.0f;
#pragma unroll
    for (int l = 0; l < LL; ++l) {
      float wv = swv[l];
      F = fmaf(wv, fmaxf(F, 0.0f), (1.0f - wv) * smc[l * PTS_PER_BLOCK + j]);
    }
    int idx = pbase + j;
    if (idx < NPOINTS) {
      float e = EXP2F(F * C_AA);              // exp(-F/0.1)
      out[idx] = C_GLN2 * LOG2F(1.0f + e);    // 0.1 * ln(1 + e)
    }
  }
}

extern "C" void kernel_launch(void* const* d_in, const int* in_sizes, int n_in,
                              void* d_out, int out_size, void* d_ws, size_t ws_size,
                              hipStream_t stream) {
  const float* xs = (const float*)d_in[0];     // [N, D]
  const float* mus = (const float*)d_in[1];    // [L, D, K]
  const float* alphas = (const float*)d_in[2]; // [L, K]
  const float* wsv = (const float*)d_in[3];    // [L]
  float* out = (float*)d_out;
  float* wsbuf = (float*)d_ws;                 // needs 26136 B

  prep_kernel<<<1, 512, 0, stream>>>(mus, alphas, wsv, wsbuf);

  const int blocks = (NPOINTS + PTS_PER_BLOCK - 1) / PTS_PER_BLOCK;  // 977
  multiinf_kernel<<<blocks, TPB, 0, stream>>>(xs, wsbuf, out);
}

// Round 3
// 131.828 us; speedup vs baseline: 1.7756x; 1.4395x over previous
//
#include <hip/hip_runtime.h>
#include <math.h>

// Problem constants (reference: N=250000, D=16, L=6, K=64, gamma=0.1)
#define NPOINTS 250000
#define LL 6
#define DD 16
#define KK 64
#define TPB 384            // 6 waves; wave w handles layer w for the block's 256 points
#define PTS_PER_BLOCK 256
#define NTILES 16          // 16 MFMA tiles of 16 points each

// ws float layout: [mu frags 6144][aa 384][wv 6]
// mu frag region: 96 units of 256B; unit u = ((l*4+cb)*2 + s)*2 + h
//   (s: 0=hi,1=lo; h: dim-half). Within unit: comp c (0..15) x 16B (8 bf16, dims h*8..h*8+7)
#define FRAG_FLOATS 6144
#define AA_OFF 6144
#define WV_OFF  6528
#define WS_FLOATS 6534

typedef __attribute__((ext_vector_type(8))) short bf16x8;
typedef __attribute__((ext_vector_type(4))) float f32x4;

#if __has_builtin(__builtin_amdgcn_exp2f)
#define EXP2F(x) __builtin_amdgcn_exp2f(x)
#else
#define EXP2F(x) exp2f(x)
#endif
#if __has_builtin(__builtin_amdgcn_logf)
#define LOG2F(x) __builtin_amdgcn_logf(x)
#else
#define LOG2F(x) log2f(x)
#endif
#if __has_builtin(__builtin_amdgcn_sqrtf)
#define SQRTF(x) __builtin_amdgcn_sqrtf(x)
#else
#define SQRTF(x) sqrtf(x)
#endif

#define C_D2   (-7.213475204444817f)    // -5 * log2(e)
#define C_AA   (-14.426950408889634f)   // -10 * log2(e)
#define C_GLN2 (0.06931471805599453f)   // gamma * ln(2)
#define PI_F   (3.14159265358979323846f)

__device__ __forceinline__ ushort bf16_rne(float f) {
  unsigned u = __float_as_uint(f);
  unsigned r = u + 0x7FFFu + ((u >> 16) & 1u);
  return (ushort)(r >> 16);
}

// per-element: exp2( C_D2 * acos(clip(x))^2 + aa )
__device__ __forceinline__ float term(float x, float aa) {
  float cx = __builtin_amdgcn_fmed3f(x, -1.0f + 1e-7f, 1.0f - 1e-7f);
  float ax = fabsf(cx);
  // Hastings 4-term acos (A&S 4.4.45), |err| <= 6.8e-5 rad
  float pp = fmaf(ax, -0.0187292991f, 0.0742610004f);
  pp = fmaf(pp, ax, -0.2121143997f);
  pp = fmaf(pp, ax, 1.5707288000f);
  float r = SQRTF(1.0f - ax) * pp;
  float dist = (cx < 0.0f) ? (PI_F - r) : r;
  float t2 = fmaf(dist * dist, C_D2, aa);
  return EXP2F(t2);
}

__global__ void prep_kernel(const float* __restrict__ mus,    // [L, D, K]
                            const float* __restrict__ alphas, // [L, K]
                            const float* __restrict__ wsv,    // [L]
                            float* __restrict__ wsbuf) {
  int t = threadIdx.x;
  if (t < LL * KK) {
    int l = t >> 6, k = t & 63;
    int cb = k >> 4, c = k & 15;
    const float* colp = mus + l * (DD * KK) + k;  // stride KK over d
    float v[DD];
    float ss = 0.0f;
#pragma unroll
    for (int d = 0; d < DD; ++d) {
      v[d] = colp[d * KK];
      ss = fmaf(v[d], v[d], ss);
    }
    float inv = 1.0f / sqrtf(ss);
    ushort hs[DD], ls[DD];
#pragma unroll
    for (int d = 0; d < DD; ++d) {
      float vn = v[d] * inv;
      ushort h = bf16_rne(vn);
      float hf = __uint_as_float((unsigned)h << 16);
      hs[d] = h;
      ls[d] = bf16_rne(vn - hf);
    }
    ushort* wsu = (ushort*)wsbuf;
#pragma unroll
    for (int s = 0; s < 2; ++s) {
#pragma unroll
      for (int h = 0; h < 2; ++h) {
        int u = ((l * 4 + cb) * 2 + s) * 2 + h;
        int base = u * 128 + c * 8;
#pragma unroll
        for (int j = 0; j < 8; ++j)
          wsu[base + j] = (s == 0) ? hs[h * 8 + j] : ls[h * 8 + j];
      }
    }
    wsbuf[AA_OFF + t] = C_AA * alphas[t];
  } else if (t < LL * KK + LL) {
    int l = t - LL * KK;
    float w = wsv[l];
    wsbuf[WV_OFF + l] = expf(-w * w);
  }
}

#define SWZ_ADD(S, OFF) \
  { S += __int_as_float(__builtin_amdgcn_ds_swizzle(__float_as_int(S), OFF)); }

__global__ __launch_bounds__(TPB, 4) void
multiinf_kernel(const float* __restrict__ xs,
                const float* __restrict__ wsbuf,
                float* __restrict__ out) {
  __shared__ float wsm[WS_FLOATS + 2];          // mu frags + aa + wv (mirror of ws)
  __shared__ uint4 sxu[PTS_PER_BLOCK * 5];      // per point 80B: [hi d0-7][hi d8-15][lo d0-7][lo d8-15][pad]
  __shared__ float smc[LL * PTS_PER_BLOCK];     // mincosts[l][point]

  for (int i = threadIdx.x; i < WS_FLOATS; i += TPB) wsm[i] = wsbuf[i];

  const int pbase = blockIdx.x * PTS_PER_BLOCK;

  // Stage x: convert each point's 16 fp32 dims to bf16 hi/lo A-fragment layout
  if (threadIdx.x < PTS_PER_BLOCK) {
    int p = threadIdx.x;
    int gidx = pbase + p;
    float v[DD];
    if (gidx < NPOINTS) {
      const float4* x4 = (const float4*)(xs + (size_t)gidx * DD);
#pragma unroll
      for (int j = 0; j < 4; ++j) {
        float4 a = x4[j];
        v[j * 4 + 0] = a.x; v[j * 4 + 1] = a.y; v[j * 4 + 2] = a.z; v[j * 4 + 3] = a.w;
      }
    } else {
#pragma unroll
      for (int d = 0; d < DD; ++d) v[d] = 0.0f;
    }
    unsigned hw[8], lw[8];
#pragma unroll
    for (int i = 0; i < 8; ++i) {
      ushort h0 = bf16_rne(v[2 * i]);
      ushort h1 = bf16_rne(v[2 * i + 1]);
      float hf0 = __uint_as_float((unsigned)h0 << 16);
      float hf1 = __uint_as_float((unsigned)h1 << 16);
      ushort l0 = bf16_rne(v[2 * i] - hf0);
      ushort l1 = bf16_rne(v[2 * i + 1] - hf1);
      hw[i] = (unsigned)h0 | ((unsigned)h1 << 16);
      lw[i] = (unsigned)l0 | ((unsigned)l1 << 16);
    }
    sxu[p * 5 + 0] = make_uint4(hw[0], hw[1], hw[2], hw[3]);
    sxu[p * 5 + 1] = make_uint4(hw[4], hw[5], hw[6], hw[7]);
    sxu[p * 5 + 2] = make_uint4(lw[0], lw[1], lw[2], lw[3]);
    sxu[p * 5 + 3] = make_uint4(lw[4], lw[5], lw[6], lw[7]);
  }
  __syncthreads();

  const int w = threadIdx.x >> 6;    // layer
  const int lane = threadIdx.x & 63;
  const int c = lane & 15;           // comp-in-block (B col / C col)
  const int q = lane >> 4;           // quad

  // B fragments for this wave's layer: resident in registers for all tiles
  bf16x8 Bh[4], Bl[4];
  float aav[4];
  const char* fragbase = (const char*)wsm;
#pragma unroll
  for (int cb = 0; cb < 4; ++cb) {
    int u1 = (((w * 4 + cb) * 2 + 0) * 2 + (q & 1));
    int u2 = (((w * 4 + cb) * 2 + 1) * 2 + (q & 1));
    Bh[cb] = *(const bf16x8*)(fragbase + u1 * 256 + c * 16);
    Bl[cb] = *(const bf16x8*)(fragbase + u2 * 256 + c * 16);
    aav[cb] = wsm[AA_OFF + w * 64 + cb * 16 + c];
  }

  float* smcw = smc + w * PTS_PER_BLOCK;
  const char* sxb = (const char*)sxu;

  for (int t = 0; t < NTILES; ++t) {
    // A fragment: point m = c, K-dim = [xhi(16); xlo(16)], slice by quad
    bf16x8 A = *(const bf16x8*)(sxb + (t * 16 + c) * 80 + q * 16);

    float S0 = 0.0f, S1 = 0.0f, S2 = 0.0f, S3 = 0.0f;
#pragma unroll
    for (int cb = 0; cb < 4; ++cb) {
      f32x4 acc = {0.0f, 0.0f, 0.0f, 0.0f};
      acc = __builtin_amdgcn_mfma_f32_16x16x32_bf16(A, Bh[cb], acc, 0, 0, 0);
      acc = __builtin_amdgcn_mfma_f32_16x16x32_bf16(A, Bl[cb], acc, 0, 0, 0);
      S0 += term(acc[0], aav[cb]);
      S1 += term(acc[1], aav[cb]);
      S2 += term(acc[2], aav[cb]);
      S3 += term(acc[3], aav[cb]);
    }
    // sum over the 16 comp-lanes (butterfly within 16-lane groups)
    SWZ_ADD(S0, 0x041F) SWZ_ADD(S1, 0x041F) SWZ_ADD(S2, 0x041F) SWZ_ADD(S3, 0x041F)
    SWZ_ADD(S0, 0x081F) SWZ_ADD(S1, 0x081F) SWZ_ADD(S2, 0x081F) SWZ_ADD(S3, 0x081F)
    SWZ_ADD(S0, 0x101F) SWZ_ADD(S1, 0x101F) SWZ_ADD(S2, 0x101F) SWZ_ADD(S3, 0x101F)
    SWZ_ADD(S0, 0x201F) SWZ_ADD(S1, 0x201F) SWZ_ADD(S2, 0x201F) SWZ_ADD(S3, 0x201F)

    if (c == 0) {
      // rows held by this lane: q*4 + r
      smcw[t * 16 + q * 4 + 0] = C_GLN2 * LOG2F(S0);
      smcw[t * 16 + q * 4 + 1] = C_GLN2 * LOG2F(S1);
      smcw[t * 16 + q * 4 + 2] = C_GLN2 * LOG2F(S2);
      smcw[t * 16 + q * 4 + 3] = C_GLN2 * LOG2F(S3);
    }
  }
  __syncthreads();

  // Recurrence + smooth-min epilogue: one thread per point
  if (threadIdx.x < PTS_PER_BLOCK) {
    int j = threadIdx.x;
    float F = 0.0f;
#pragma unroll
    for (int l = 0; l < LL; ++l) {
      float wv = wsm[WV_OFF + l];
      F = fmaf(wv, fmaxf(F, 0.0f), (1.0f - wv) * smc[l * PTS_PER_BLOCK + j]);
    }
    int idx = pbase + j;
    if (idx < NPOINTS) {
      float e = EXP2F(F * C_AA);              // exp(-F/0.1)
      out[idx] = C_GLN2 * LOG2F(1.0f + e);    // 0.1 * ln(1 + e)
    }
  }
}

extern "C" void kernel_launch(void* const* d_in, const int* in_sizes, int n_in,
                              void* d_out, int out_size, void* d_ws, size_t ws_size,
                              hipStream_t stream) {
  const float* xs = (const float*)d_in[0];     // [N, D]
  const float* mus = (const float*)d_in[1];    // [L, D, K]
  const float* alphas = (const float*)d_in[2]; // [L, K]
  const float* wsv = (const float*)d_in[3];    // [L]
  float* out = (float*)d_out;
  float* wsbuf = (float*)d_ws;                 // needs 26136 B

  prep_kernel<<<1, 512, 0, stream>>>(mus, alphas, wsv, wsbuf);

  const int blocks = (NPOINTS + PTS_PER_BLOCK - 1) / PTS_PER_BLOCK;  // 977
  multiinf_kernel<<<blocks, TPB, 0, stream>>>(xs, wsbuf, out);
}

// Round 4
// 125.423 us; speedup vs baseline: 1.8663x; 1.0511x over previous
//
#include <hip/hip_runtime.h>
#include <math.h>

// Problem constants (reference: N=250000, D=16, L=6, K=64, gamma=0.1)
#define NPOINTS 250000
#define LL 6
#define DD 16
#define KK 64
#define TPB 384            // 6 waves; wave w handles layer w for the block's 256 points
#define PTS_PER_BLOCK 256
#define NTILES 16          // 16 MFMA tiles of 16 points each

// LDS layout (byte offsets into smem), phase-aliased:
//  Phase A: musc: column j of layer l at (l*64+j)*64, 24576 B
//           per column: [hi d0-7 16B][hi d8-15][lo d0-7][lo d8-15]
//  Phase B: sxu: point p at p*80 (80B: hi d0-7, hi d8-15, lo d0-7, lo d8-15, pad), 20480 B
//           smc: float at SMC_OFF + (l*256+p)*4, 6144 B
//  swv: 6 floats at SWV_OFF (never aliased)
#define SMC_OFF 20480
#define SWV_OFF 26624
#define LDS_BYTES (SWV_OFF + 32)

typedef __attribute__((ext_vector_type(8))) short bf16x8;
typedef __attribute__((ext_vector_type(4))) float f32x4;

#if __has_builtin(__builtin_amdgcn_exp2f)
#define EXP2F(x) __builtin_amdgcn_exp2f(x)
#else
#define EXP2F(x) exp2f(x)
#endif
#if __has_builtin(__builtin_amdgcn_logf)
#define LOG2F(x) __builtin_amdgcn_logf(x)
#else
#define LOG2F(x) log2f(x)
#endif
#if __has_builtin(__builtin_amdgcn_sqrtf)
#define SQRTF(x) __builtin_amdgcn_sqrtf(x)
#else
#define SQRTF(x) sqrtf(x)
#endif

#define C_D2   (-7.213475204444817f)    // -5 * log2(e)
#define C_AA   (-14.426950408889634f)   // -10 * log2(e)
#define C_GLN2 (0.06931471805599453f)   // gamma * ln(2)
#define PI_F   (3.14159265358979323846f)

__device__ __forceinline__ ushort bf16_rne(float f) {
  unsigned u = __float_as_uint(f);
  unsigned r = u + 0x7FFFu + ((u >> 16) & 1u);
  return (ushort)(r >> 16);
}

// per-element: exp2( C_D2 * acos(clip(x))^2 + aa )
__device__ __forceinline__ float term(float x, float aa) {
  float cx = __builtin_amdgcn_fmed3f(x, -1.0f + 1e-7f, 1.0f - 1e-7f);
  float ax = fabsf(cx);
  // Hastings 4-term acos (A&S 4.4.45), |err| <= 6.8e-5 rad
  float pp = fmaf(ax, -0.0187292991f, 0.0742610004f);
  pp = fmaf(pp, ax, -0.2121143997f);
  pp = fmaf(pp, ax, 1.5707288000f);
  float r = SQRTF(1.0f - ax) * pp;
  float dist = (cx < 0.0f) ? (PI_F - r) : r;
  float t2 = fmaf(dist * dist, C_D2, aa);
  return EXP2F(t2);
}

#define SWZ_ADD(S, OFF) \
  { S += __int_as_float(__builtin_amdgcn_ds_swizzle(__float_as_int(S), OFF)); }

__global__ __launch_bounds__(TPB, 6) void
multiinf_kernel(const float* __restrict__ xs,
                const float* __restrict__ mus,    // [L, D, K]
                const float* __restrict__ alphas, // [L, K]
                const float* __restrict__ wsv,    // [L]
                float* __restrict__ out) {
  __shared__ __align__(16) char smem[LDS_BYTES];
  float* swv = (float*)(smem + SWV_OFF);
  float* smc = (float*)(smem + SMC_OFF);

  const int tid = threadIdx.x;
  const int w = tid >> 6;            // wave = layer
  const int lane = tid & 63;
  const int c = lane & 15;           // MFMA col (comp-in-block / point-in-tile)
  const int q = lane >> 4;           // quad
  const int h = q & 1;               // dim half
  const int pbase = blockIdx.x * PTS_PER_BLOCK;

  // Prefetch this thread's x point (threads 0..255) to overlap with phase A
  float xv[DD];
  {
    int gidx = pbase + tid;
    if (tid < PTS_PER_BLOCK && gidx < NPOINTS) {
      const float4* x4 = (const float4*)(xs + (size_t)gidx * DD);
#pragma unroll
      for (int j = 0; j < 4; ++j) {
        float4 a = x4[j];
        xv[j * 4 + 0] = a.x; xv[j * 4 + 1] = a.y;
        xv[j * 4 + 2] = a.z; xv[j * 4 + 3] = a.w;
      }
    } else {
#pragma unroll
      for (int d = 0; d < DD; ++d) xv[d] = 0.0f;
    }
  }

  // ---- Phase A: wave w normalizes column `lane` of layer w, splits bf16 hi/lo,
  //      writes 64B column record into musc scratch ----
  {
    const float* colp = mus + w * (DD * KK) + lane;   // stride KK over d (coalesced per d)
    float v[DD];
    float ss = 0.0f;
#pragma unroll
    for (int d = 0; d < DD; ++d) { v[d] = colp[d * KK]; ss = fmaf(v[d], v[d], ss); }
    float inv = 1.0f / sqrtf(ss);
    unsigned hw[8], lw[8];
#pragma unroll
    for (int i = 0; i < 8; ++i) {
      float a0 = v[2 * i] * inv;
      float a1 = v[2 * i + 1] * inv;
      ushort h0 = bf16_rne(a0), h1 = bf16_rne(a1);
      float hf0 = __uint_as_float((unsigned)h0 << 16);
      float hf1 = __uint_as_float((unsigned)h1 << 16);
      ushort l0 = bf16_rne(a0 - hf0), l1 = bf16_rne(a1 - hf1);
      hw[i] = (unsigned)h0 | ((unsigned)h1 << 16);
      lw[i] = (unsigned)l0 | ((unsigned)l1 << 16);
    }
    uint4* colq = (uint4*)(smem + (w * 64 + lane) * 64);
    colq[0] = make_uint4(hw[0], hw[1], hw[2], hw[3]);
    colq[1] = make_uint4(hw[4], hw[5], hw[6], hw[7]);
    colq[2] = make_uint4(lw[0], lw[1], lw[2], lw[3]);
    colq[3] = make_uint4(lw[4], lw[5], lw[6], lw[7]);
  }
  float av = C_AA * alphas[w * 64 + lane];   // alpha of column `lane`
  if (tid < LL) { float t = wsv[tid]; swv[tid] = expf(-t * t); }
  __syncthreads();

  // ---- Read B fragments into registers (resident for the whole main loop) ----
  bf16x8 Bh[4], Bl[4];
  float aav[4];
#pragma unroll
  for (int cb = 0; cb < 4; ++cb) {
    const char* base = smem + (w * 64 + cb * 16 + c) * 64 + h * 16;
    Bh[cb] = *(const bf16x8*)(base);
    Bl[cb] = *(const bf16x8*)(base + 32);
    aav[cb] = __shfl(av, cb * 16 + c, 64);
  }
  __syncthreads();   // all frag reads done; musc region now reusable

  // ---- Phase B: stage x A-fragments (bf16 hi/lo) into sxu ----
  if (tid < PTS_PER_BLOCK) {
    unsigned hw[8], lw[8];
#pragma unroll
    for (int i = 0; i < 8; ++i) {
      ushort h0 = bf16_rne(xv[2 * i]);
      ushort h1 = bf16_rne(xv[2 * i + 1]);
      float hf0 = __uint_as_float((unsigned)h0 << 16);
      float hf1 = __uint_as_float((unsigned)h1 << 16);
      ushort l0 = bf16_rne(xv[2 * i] - hf0);
      ushort l1 = bf16_rne(xv[2 * i + 1] - hf1);
      hw[i] = (unsigned)h0 | ((unsigned)h1 << 16);
      lw[i] = (unsigned)l0 | ((unsigned)l1 << 16);
    }
    uint4* pq = (uint4*)(smem + tid * 80);
    pq[0] = make_uint4(hw[0], hw[1], hw[2], hw[3]);
    pq[1] = make_uint4(hw[4], hw[5], hw[6], hw[7]);
    pq[2] = make_uint4(lw[0], lw[1], lw[2], lw[3]);
    pq[3] = make_uint4(lw[4], lw[5], lw[6], lw[7]);
  }
  __syncthreads();

  // ---- Main loop: 16 tiles of 16 points ----
  float* smcw = smc + w * PTS_PER_BLOCK;
  for (int t = 0; t < NTILES; ++t) {
    // A fragment: point m = c of tile t, K = [xhi(16); xlo(16)], sliced by quad
    bf16x8 A = *(const bf16x8*)(smem + (t * 16 + c) * 80 + q * 16);

    float S0 = 0.0f, S1 = 0.0f, S2 = 0.0f, S3 = 0.0f;
#pragma unroll
    for (int cb = 0; cb < 4; ++cb) {
      f32x4 acc = {0.0f, 0.0f, 0.0f, 0.0f};
      acc = __builtin_amdgcn_mfma_f32_16x16x32_bf16(A, Bh[cb], acc, 0, 0, 0);
      acc = __builtin_amdgcn_mfma_f32_16x16x32_bf16(A, Bl[cb], acc, 0, 0, 0);
      S0 += term(acc[0], aav[cb]);
      S1 += term(acc[1], aav[cb]);
      S2 += term(acc[2], aav[cb]);
      S3 += term(acc[3], aav[cb]);
    }
    // sum over the 16 comp-lanes (xor butterfly over lane bits 0..3)
    SWZ_ADD(S0, 0x041F) SWZ_ADD(S1, 0x041F) SWZ_ADD(S2, 0x041F) SWZ_ADD(S3, 0x041F)
    SWZ_ADD(S0, 0x081F) SWZ_ADD(S1, 0x081F) SWZ_ADD(S2, 0x081F) SWZ_ADD(S3, 0x081F)
    SWZ_ADD(S0, 0x101F) SWZ_ADD(S1, 0x101F) SWZ_ADD(S2, 0x101F) SWZ_ADD(S3, 0x101F)
    SWZ_ADD(S0, 0x201F) SWZ_ADD(S1, 0x201F) SWZ_ADD(S2, 0x201F) SWZ_ADD(S3, 0x201F)

    if (c == 0) {   // rows q*4+r; store raw sums, log applied in epilogue
      smcw[t * 16 + q * 4 + 0] = S0;
      smcw[t * 16 + q * 4 + 1] = S1;
      smcw[t * 16 + q * 4 + 2] = S2;
      smcw[t * 16 + q * 4 + 3] = S3;
    }
  }
  __syncthreads();

  // ---- Epilogue: recurrence + smooth-min, one thread per point ----
  if (tid < PTS_PER_BLOCK) {
    float F = 0.0f;
#pragma unroll
    for (int l = 0; l < LL; ++l) {
      float wv = swv[l];
      float mc = C_GLN2 * LOG2F(smc[l * PTS_PER_BLOCK + tid]);  // gamma*ln(S)
      F = fmaf(wv, fmaxf(F, 0.0f), (1.0f - wv) * mc);
    }
    int idx = pbase + tid;
    if (idx < NPOINTS) {
      float e = EXP2F(F * C_AA);              // exp(-F/0.1)
      out[idx] = C_GLN2 * LOG2F(1.0f + e);    // 0.1 * ln(1 + e)
    }
  }
}

extern "C" void kernel_launch(void* const* d_in, const int* in_sizes, int n_in,
                              void* d_out, int out_size, void* d_ws, size_t ws_size,
                              hipStream_t stream) {
  const float* xs = (const float*)d_in[0];     // [N, D]
  const float* mus = (const float*)d_in[1];    // [L, D, K]
  const float* alphas = (const float*)d_in[2]; // [L, K]
  const float* wsv = (const float*)d_in[3];    // [L]
  float* out = (float*)d_out;
  (void)d_ws; (void)ws_size;

  const int blocks = (NPOINTS + PTS_PER_BLOCK - 1) / PTS_PER_BLOCK;  // 977
  multiinf_kernel<<<blocks, TPB, 0, stream>>>(xs, mus, alphas, wsv, out);
}

// Round 5
// 122.768 us; speedup vs baseline: 1.9066x; 1.0216x over previous
//
#include <hip/hip_runtime.h>
#include <math.h>

// Problem constants (reference: N=250000, D=16, L=6, K=64, gamma=0.1)
#define NPOINTS 250000
#define LL 6
#define DD 16
#define KK 64
#define TPB 384            // 6 waves; wave w handles layer w for the block's 256 points
#define PTS_PER_BLOCK 256
#define NTILES 16          // 16 MFMA tiles of 16 points each

// LDS layout (byte offsets into smem), phase-aliased:
//  Phase A: musc: column j of layer l at (l*64+j)*64, 24576 B
//  Phase B: sxu: point p at p*80 (80B: hi d0-7, hi d8-15, lo d0-7, lo d8-15, pad), 20480 B
//           smc: float at SMC_OFF + (l*256+p)*4, 6144 B
//  swv: 6 floats at SWV_OFF (never aliased)
#define SMC_OFF 20480
#define SWV_OFF 26624
#define LDS_BYTES (SWV_OFF + 32)

typedef __attribute__((ext_vector_type(8))) short bf16x8;
typedef __attribute__((ext_vector_type(4))) float f32x4;

#if __has_builtin(__builtin_amdgcn_exp2f)
#define EXP2F(x) __builtin_amdgcn_exp2f(x)
#else
#define EXP2F(x) exp2f(x)
#endif
#if __has_builtin(__builtin_amdgcn_logf)
#define LOG2F(x) __builtin_amdgcn_logf(x)
#else
#define LOG2F(x) log2f(x)
#endif
#if __has_builtin(__builtin_amdgcn_sqrtf)
#define SQRTF(x) __builtin_amdgcn_sqrtf(x)
#else
#define SQRTF(x) sqrtf(x)
#endif

#define C_AA   (-14.426950408889634f)   // -10 * log2(e)
#define C_GLN2 (0.06931471805599453f)   // gamma * ln(2)

// acos poly folded with SQ_C = sqrt(5*log2e) = 2.6857914 so that
// u = SQ_C * acos(clip(x)) and t2 = -u^2 + aa = log2-arg of the exp term.
#define AC3 (-0.05030299f)
#define AC2 (0.19944957f)
#define AC1 (-0.56969503f)
#define AC0 (4.2186499f)
#define PI_HAT (8.4376625f)             // SQ_C * pi

__device__ __forceinline__ ushort bf16_rne(float f) {
  unsigned u = __float_as_uint(f);
  unsigned r = u + 0x7FFFu + ((u >> 16) & 1u);
  return (ushort)(r >> 16);
}

// per-element: exp2( -5*log2e*acos(clip(x))^2 + aa )
__device__ __forceinline__ float term(float x, float aa) {
  float cx = __builtin_amdgcn_fmed3f(x, -1.0f + 1e-7f, 1.0f - 1e-7f);
  float ax = fabsf(cx);
  float pp = fmaf(ax, AC3, AC2);
  pp = fmaf(pp, ax, AC1);
  pp = fmaf(pp, ax, AC0);
  float uh = SQRTF(1.0f - ax) * pp;           // SQ_C * acos(|x|)
  float u = (cx < 0.0f) ? (PI_HAT - uh) : uh; // SQ_C * acos(x)
  float t2 = fmaf(u, -u, aa);
  return EXP2F(t2);
}

// Inclusive-scan add over DPP 16-lane rows; after shr 1,2,4,8 lane 15 of each
// row holds the row sum. Full-rate VALU, no LDS pipe.
#define DPP_ADD(S, CTRL)                                                     \
  {                                                                          \
    int _t = __builtin_amdgcn_update_dpp(0, __float_as_int(S), CTRL, 0xF,    \
                                         0xF, true);                         \
    S += __int_as_float(_t);                                                 \
  }
#define ROW_SHR1 0x111
#define ROW_SHR2 0x112
#define ROW_SHR4 0x114
#define ROW_SHR8 0x118

__global__ __launch_bounds__(TPB, 6) void
multiinf_kernel(const float* __restrict__ xs,
                const float* __restrict__ mus,    // [L, D, K]
                const float* __restrict__ alphas, // [L, K]
                const float* __restrict__ wsv,    // [L]
                float* __restrict__ out) {
  __shared__ __align__(16) char smem[LDS_BYTES];
  float* swv = (float*)(smem + SWV_OFF);
  float* smc = (float*)(smem + SMC_OFF);

  const int tid = threadIdx.x;
  const int w = tid >> 6;            // wave = layer
  const int lane = tid & 63;
  const int c = lane & 15;           // MFMA col (comp-in-block / point-in-tile)
  const int q = lane >> 4;           // quad
  const int h = q & 1;               // dim half
  const int pbase = blockIdx.x * PTS_PER_BLOCK;

  // Prefetch this thread's x point (threads 0..255) to overlap with phase A
  float xv[DD];
  {
    int gidx = pbase + tid;
    if (tid < PTS_PER_BLOCK && gidx < NPOINTS) {
      const float4* x4 = (const float4*)(xs + (size_t)gidx * DD);
#pragma unroll
      for (int j = 0; j < 4; ++j) {
        float4 a = x4[j];
        xv[j * 4 + 0] = a.x; xv[j * 4 + 1] = a.y;
        xv[j * 4 + 2] = a.z; xv[j * 4 + 3] = a.w;
      }
    } else {
#pragma unroll
      for (int d = 0; d < DD; ++d) xv[d] = 0.0f;
    }
  }

  // ---- Phase A: wave w normalizes column `lane` of layer w, splits bf16 hi/lo,
  //      writes 64B column record into musc scratch ----
  {
    const float* colp = mus + w * (DD * KK) + lane;   // stride KK over d (coalesced per d)
    float v[DD];
    float ss = 0.0f;
#pragma unroll
    for (int d = 0; d < DD; ++d) { v[d] = colp[d * KK]; ss = fmaf(v[d], v[d], ss); }
    float inv = 1.0f / sqrtf(ss);
    unsigned hw[8], lw[8];
#pragma unroll
    for (int i = 0; i < 8; ++i) {
      float a0 = v[2 * i] * inv;
      float a1 = v[2 * i + 1] * inv;
      ushort h0 = bf16_rne(a0), h1 = bf16_rne(a1);
      float hf0 = __uint_as_float((unsigned)h0 << 16);
      float hf1 = __uint_as_float((unsigned)h1 << 16);
      ushort l0 = bf16_rne(a0 - hf0), l1 = bf16_rne(a1 - hf1);
      hw[i] = (unsigned)h0 | ((unsigned)h1 << 16);
      lw[i] = (unsigned)l0 | ((unsigned)l1 << 16);
    }
    uint4* colq = (uint4*)(smem + (w * 64 + lane) * 64);
    colq[0] = make_uint4(hw[0], hw[1], hw[2], hw[3]);
    colq[1] = make_uint4(hw[4], hw[5], hw[6], hw[7]);
    colq[2] = make_uint4(lw[0], lw[1], lw[2], lw[3]);
    colq[3] = make_uint4(lw[4], lw[5], lw[6], lw[7]);
  }
  float av = C_AA * alphas[w * 64 + lane];   // alpha of column `lane`
  if (tid < LL) { float t = wsv[tid]; swv[tid] = expf(-t * t); }
  __syncthreads();

  // ---- Read B fragments into registers (resident for the whole main loop) ----
  bf16x8 Bh[4], Bl[4];
  float aav[4];
#pragma unroll
  for (int cb = 0; cb < 4; ++cb) {
    const char* base = smem + (w * 64 + cb * 16 + c) * 64 + h * 16;
    Bh[cb] = *(const bf16x8*)(base);
    Bl[cb] = *(const bf16x8*)(base + 32);
    aav[cb] = __shfl(av, cb * 16 + c, 64);
  }
  __syncthreads();   // all frag reads done; musc region now reusable

  // ---- Phase B: stage x A-fragments (bf16 hi/lo) into sxu ----
  if (tid < PTS_PER_BLOCK) {
    unsigned hw[8], lw[8];
#pragma unroll
    for (int i = 0; i < 8; ++i) {
      ushort h0 = bf16_rne(xv[2 * i]);
      ushort h1 = bf16_rne(xv[2 * i + 1]);
      float hf0 = __uint_as_float((unsigned)h0 << 16);
      float hf1 = __uint_as_float((unsigned)h1 << 16);
      ushort l0 = bf16_rne(xv[2 * i] - hf0);
      ushort l1 = bf16_rne(xv[2 * i + 1] - hf1);
      hw[i] = (unsigned)h0 | ((unsigned)h1 << 16);
      lw[i] = (unsigned)l0 | ((unsigned)l1 << 16);
    }
    uint4* pq = (uint4*)(smem + tid * 80);
    pq[0] = make_uint4(hw[0], hw[1], hw[2], hw[3]);
    pq[1] = make_uint4(hw[4], hw[5], hw[6], hw[7]);
    pq[2] = make_uint4(lw[0], lw[1], lw[2], lw[3]);
    pq[3] = make_uint4(lw[4], lw[5], lw[6], lw[7]);
  }
  __syncthreads();

  // ---- Main loop: 16 tiles of 16 points ----
  float* smcw = smc + w * PTS_PER_BLOCK;
  for (int t = 0; t < NTILES; ++t) {
    // A fragment: point m = c of tile t, K = [xhi(16); xlo(16)], sliced by quad
    bf16x8 A = *(const bf16x8*)(smem + (t * 16 + c) * 80 + q * 16);

    float S0 = 0.0f, S1 = 0.0f, S2 = 0.0f, S3 = 0.0f;
#pragma unroll
    for (int cb = 0; cb < 4; ++cb) {
      f32x4 acc = {0.0f, 0.0f, 0.0f, 0.0f};
      acc = __builtin_amdgcn_mfma_f32_16x16x32_bf16(A, Bh[cb], acc, 0, 0, 0);
      acc = __builtin_amdgcn_mfma_f32_16x16x32_bf16(A, Bl[cb], acc, 0, 0, 0);
      S0 += term(acc[0], aav[cb]);
      S1 += term(acc[1], aav[cb]);
      S2 += term(acc[2], aav[cb]);
      S3 += term(acc[3], aav[cb]);
    }
    // sum over the 16 comp-lanes: DPP row scan, total lands in lane 15 of row
    DPP_ADD(S0, ROW_SHR1) DPP_ADD(S1, ROW_SHR1) DPP_ADD(S2, ROW_SHR1) DPP_ADD(S3, ROW_SHR1)
    DPP_ADD(S0, ROW_SHR2) DPP_ADD(S1, ROW_SHR2) DPP_ADD(S2, ROW_SHR2) DPP_ADD(S3, ROW_SHR2)
    DPP_ADD(S0, ROW_SHR4) DPP_ADD(S1, ROW_SHR4) DPP_ADD(S2, ROW_SHR4) DPP_ADD(S3, ROW_SHR4)
    DPP_ADD(S0, ROW_SHR8) DPP_ADD(S1, ROW_SHR8) DPP_ADD(S2, ROW_SHR8) DPP_ADD(S3, ROW_SHR8)

    if (c == 15) {   // rows q*4+r; store raw sums, log applied in epilogue
      smcw[t * 16 + q * 4 + 0] = S0;
      smcw[t * 16 + q * 4 + 1] = S1;
      smcw[t * 16 + q * 4 + 2] = S2;
      smcw[t * 16 + q * 4 + 3] = S3;
    }
  }
  __syncthreads();

  // ---- Epilogue: recurrence + smooth-min, one thread per point ----
  if (tid < PTS_PER_BLOCK) {
    float F = 0.0f;
#pragma unroll
    for (int l = 0; l < LL; ++l) {
      float wv = swv[l];
      float mc = C_GLN2 * LOG2F(smc[l * PTS_PER_BLOCK + tid]);  // gamma*ln(S)
      F = fmaf(wv, fmaxf(F, 0.0f), (1.0f - wv) * mc);
    }
    int idx = pbase + tid;
    if (idx < NPOINTS) {
      float e = EXP2F(F * C_AA);              // exp(-F/0.1)
      out[idx] = C_GLN2 * LOG2F(1.0f + e);    // 0.1 * ln(1 + e)
    }
  }
}

extern "C" void kernel_launch(void* const* d_in, const int* in_sizes, int n_in,
                              void* d_out, int out_size, void* d_ws, size_t ws_size,
                              hipStream_t stream) {
  const float* xs = (const float*)d_in[0];     // [N, D]
  const float* mus = (const float*)d_in[1];    // [L, D, K]
  const float* alphas = (const float*)d_in[2]; // [L, K]
  const float* wsv = (const float*)d_in[3];    // [L]
  float* out = (float*)d_out;
  (void)d_ws; (void)ws_size;

  const int blocks = (NPOINTS + PTS_PER_BLOCK - 1) / PTS_PER_BLOCK;  // 977
  multiinf_kernel<<<blocks, TPB, 0, stream>>>(xs, mus, alphas, wsv, out);
}

// Round 6
// 119.969 us; speedup vs baseline: 1.9511x; 1.0233x over previous
//
#include <hip/hip_runtime.h>
#include <math.h>

// Problem constants (reference: N=250000, D=16, L=6, K=64, gamma=0.1)
#define NPOINTS 250000
#define LL 6
#define DD 16
#define KK 64
#define TPB 384            // 6 waves; wave w handles layer w for the block's 256 points
#define PTS_PER_BLOCK 256
#define NTILES 16          // 16 MFMA tiles of 16 points each

// LDS layout (byte offsets into smem), phase-aliased:
//  Phase A: musc: column j of layer l at (l*64+j)*64, 24576 B
//  Phase B: sxu: point p at p*80 (80B: hi d0-7, hi d8-15, lo d0-7, lo d8-15, pad), 20480 B
//           smc: float at SMC_OFF + (l*256+p)*4, 6144 B
//  swv: 6 floats at SWV_OFF (never aliased)
#define SMC_OFF 20480
#define SWV_OFF 26624
#define LDS_BYTES (SWV_OFF + 32)

typedef __attribute__((ext_vector_type(8))) short bf16x8;
typedef __attribute__((ext_vector_type(4))) float f32x4;
typedef __attribute__((ext_vector_type(2))) float f32x2;

#if __has_builtin(__builtin_amdgcn_exp2f)
#define EXP2F(x) __builtin_amdgcn_exp2f(x)
#else
#define EXP2F(x) exp2f(x)
#endif
#if __has_builtin(__builtin_amdgcn_logf)
#define LOG2F(x) __builtin_amdgcn_logf(x)
#else
#define LOG2F(x) log2f(x)
#endif
#if __has_builtin(__builtin_amdgcn_sqrtf)
#define SQRTF(x) __builtin_amdgcn_sqrtf(x)
#else
#define SQRTF(x) sqrtf(x)
#endif

#define C_AA   (-14.426950408889634f)   // -10 * log2(e)
#define C_GLN2 (0.06931471805599453f)   // gamma * ln(2)

// acos poly folded with SQ_C = sqrt(5*log2e) = 2.6857914 so that
// u = SQ_C * acos(clip(x)) and t2 = -u^2 + aa = log2-arg of the exp term.
#define AC3 (-0.05030299f)
#define AC2 (0.19944957f)
#define AC1 (-0.56969503f)
#define AC0 (4.2186499f)
#define PI_HAT (8.4376625f)             // SQ_C * pi
#define CLIP_C (1.0f - 1e-7f)

__device__ __forceinline__ f32x2 s2(float v) { f32x2 r; r.x = v; r.y = v; return r; }

__device__ __forceinline__ ushort bf16_rne(float f) {
  unsigned u = __float_as_uint(f);
  unsigned r = u + 0x7FFFu + ((u >> 16) & 1u);
  return (ushort)(r >> 16);
}

// packed pair: exp2( -5*log2e*acos(clip(x))^2 + aa ), aa pre-splat
__device__ __forceinline__ f32x2 term2(f32x2 x, f32x2 aa) {
  // symmetric clip: ax = min(|x|, 1-1e-7); sign from raw x
  f32x2 ax = __builtin_elementwise_min(__builtin_elementwise_abs(x), s2(CLIP_C));
  f32x2 pp = __builtin_elementwise_fma(ax, s2(AC3), s2(AC2));   // v_pk_fma_f32
  pp = __builtin_elementwise_fma(pp, ax, s2(AC1));
  pp = __builtin_elementwise_fma(pp, ax, s2(AC0));
  f32x2 om = s2(1.0f) - ax;                                      // v_pk_add_f32
  f32x2 sq; sq.x = SQRTF(om.x); sq.y = SQRTF(om.y);
  f32x2 v = sq * pp;                                             // v_pk_mul_f32
  f32x2 u;
  u.x = (x.x < 0.0f) ? (PI_HAT - v.x) : v.x;
  u.y = (x.y < 0.0f) ? (PI_HAT - v.y) : v.y;
  f32x2 t2 = __builtin_elementwise_fma(u, -u, aa);               // v_pk_fma_f32
  f32x2 e; e.x = EXP2F(t2.x); e.y = EXP2F(t2.y);
  return e;
}

// DPP row-shift adds; after shr 1,2,4,8 lane 15 of each 16-row holds the sum.
#define DPP_ADD(S, CTRL)                                                     \
  {                                                                          \
    int _t = __builtin_amdgcn_update_dpp(0, __float_as_int(S), CTRL, 0xF,    \
                                         0xF, true);                         \
    S += __int_as_float(_t);                                                 \
  }
#define ROW_SHR1 0x111
#define ROW_SHR2 0x112
#define ROW_SHR4 0x114
#define ROW_SHR8 0x118

__global__ __launch_bounds__(TPB, 6) void
multiinf_kernel(const float* __restrict__ xs,
                const float* __restrict__ mus,    // [L, D, K]
                const float* __restrict__ alphas, // [L, K]
                const float* __restrict__ wsv,    // [L]
                float* __restrict__ out) {
  __shared__ __align__(16) char smem[LDS_BYTES];
  float* swv = (float*)(smem + SWV_OFF);
  float* smc = (float*)(smem + SMC_OFF);

  const int tid = threadIdx.x;
  const int w = tid >> 6;            // wave = layer
  const int lane = tid & 63;
  const int c = lane & 15;           // MFMA col (comp-in-block / point-in-tile)
  const int q = lane >> 4;           // quad
  const int h = q & 1;               // dim half
  const int pbase = blockIdx.x * PTS_PER_BLOCK;

  // Prefetch this thread's x point (threads 0..255) to overlap with phase A
  float xv[DD];
  {
    int gidx = pbase + tid;
    if (tid < PTS_PER_BLOCK && gidx < NPOINTS) {
      const float4* x4 = (const float4*)(xs + (size_t)gidx * DD);
#pragma unroll
      for (int j = 0; j < 4; ++j) {
        float4 a = x4[j];
        xv[j * 4 + 0] = a.x; xv[j * 4 + 1] = a.y;
        xv[j * 4 + 2] = a.z; xv[j * 4 + 3] = a.w;
      }
    } else {
#pragma unroll
      for (int d = 0; d < DD; ++d) xv[d] = 0.0f;
    }
  }

  // ---- Phase A: wave w normalizes column `lane` of layer w, splits bf16 hi/lo,
  //      writes 64B column record into musc scratch ----
  {
    const float* colp = mus + w * (DD * KK) + lane;   // stride KK over d (coalesced per d)
    float v[DD];
    float ss = 0.0f;
#pragma unroll
    for (int d = 0; d < DD; ++d) { v[d] = colp[d * KK]; ss = fmaf(v[d], v[d], ss); }
    float inv = 1.0f / sqrtf(ss);
    unsigned hw[8], lw[8];
#pragma unroll
    for (int i = 0; i < 8; ++i) {
      float a0 = v[2 * i] * inv;
      float a1 = v[2 * i + 1] * inv;
      ushort h0 = bf16_rne(a0), h1 = bf16_rne(a1);
      float hf0 = __uint_as_float((unsigned)h0 << 16);
      float hf1 = __uint_as_float((unsigned)h1 << 16);
      ushort l0 = bf16_rne(a0 - hf0), l1 = bf16_rne(a1 - hf1);
      hw[i] = (unsigned)h0 | ((unsigned)h1 << 16);
      lw[i] = (unsigned)l0 | ((unsigned)l1 << 16);
    }
    uint4* colq = (uint4*)(smem + (w * 64 + lane) * 64);
    colq[0] = make_uint4(hw[0], hw[1], hw[2], hw[3]);
    colq[1] = make_uint4(hw[4], hw[5], hw[6], hw[7]);
    colq[2] = make_uint4(lw[0], lw[1], lw[2], lw[3]);
    colq[3] = make_uint4(lw[4], lw[5], lw[6], lw[7]);
  }
  float av = C_AA * alphas[w * 64 + lane];   // alpha of column `lane`
  if (tid < LL) { float t = wsv[tid]; swv[tid] = expf(-t * t); }
  __syncthreads();

  // ---- Read B fragments into registers (resident for the whole main loop) ----
  bf16x8 Bh[4], Bl[4];
  f32x2 aa2[4];
#pragma unroll
  for (int cb = 0; cb < 4; ++cb) {
    const char* base = smem + (w * 64 + cb * 16 + c) * 64 + h * 16;
    Bh[cb] = *(const bf16x8*)(base);
    Bl[cb] = *(const bf16x8*)(base + 32);
    aa2[cb] = s2(__shfl(av, cb * 16 + c, 64));
  }
  __syncthreads();   // all frag reads done; musc region now reusable

  // ---- Phase B: stage x A-fragments (bf16 hi/lo) into sxu ----
  if (tid < PTS_PER_BLOCK) {
    unsigned hw[8], lw[8];
#pragma unroll
    for (int i = 0; i < 8; ++i) {
      ushort h0 = bf16_rne(xv[2 * i]);
      ushort h1 = bf16_rne(xv[2 * i + 1]);
      float hf0 = __uint_as_float((unsigned)h0 << 16);
      float hf1 = __uint_as_float((unsigned)h1 << 16);
      ushort l0 = bf16_rne(xv[2 * i] - hf0);
      ushort l1 = bf16_rne(xv[2 * i + 1] - hf1);
      hw[i] = (unsigned)h0 | ((unsigned)h1 << 16);
      lw[i] = (unsigned)l0 | ((unsigned)l1 << 16);
    }
    uint4* pq = (uint4*)(smem + tid * 80);
    pq[0] = make_uint4(hw[0], hw[1], hw[2], hw[3]);
    pq[1] = make_uint4(hw[4], hw[5], hw[6], hw[7]);
    pq[2] = make_uint4(lw[0], lw[1], lw[2], lw[3]);
    pq[3] = make_uint4(lw[4], lw[5], lw[6], lw[7]);
  }
  __syncthreads();

  // ---- Main loop: 16 tiles of 16 points, A-fragment software-prefetched ----
  float* smcw = smc + w * PTS_PER_BLOCK;
  bf16x8 A = *(const bf16x8*)(smem + (0 * 16 + c) * 80 + q * 16);
  for (int t = 0; t < NTILES; ++t) {
    // issue next tile's A read now; ~150 VALU instrs below cover the latency
    bf16x8 An = *(const bf16x8*)(smem + ((((t + 1) & 15) * 16) + c) * 80 + q * 16);

    f32x2 S01 = s2(0.0f), S23 = s2(0.0f);
#pragma unroll
    for (int cb = 0; cb < 4; ++cb) {
      f32x4 acc = {0.0f, 0.0f, 0.0f, 0.0f};
      acc = __builtin_amdgcn_mfma_f32_16x16x32_bf16(A, Bh[cb], acc, 0, 0, 0);
      acc = __builtin_amdgcn_mfma_f32_16x16x32_bf16(A, Bl[cb], acc, 0, 0, 0);
      f32x2 a01; a01.x = acc[0]; a01.y = acc[1];
      f32x2 a23; a23.x = acc[2]; a23.y = acc[3];
      S01 += term2(a01, aa2[cb]);   // v_pk_add_f32
      S23 += term2(a23, aa2[cb]);
    }
    float S0 = S01.x, S1 = S01.y, S2 = S23.x, S3 = S23.y;
    // sum over the 16 comp-lanes: DPP row scan, total lands in lane 15 of row
    DPP_ADD(S0, ROW_SHR1) DPP_ADD(S1, ROW_SHR1) DPP_ADD(S2, ROW_SHR1) DPP_ADD(S3, ROW_SHR1)
    DPP_ADD(S0, ROW_SHR2) DPP_ADD(S1, ROW_SHR2) DPP_ADD(S2, ROW_SHR2) DPP_ADD(S3, ROW_SHR2)
    DPP_ADD(S0, ROW_SHR4) DPP_ADD(S1, ROW_SHR4) DPP_ADD(S2, ROW_SHR4) DPP_ADD(S3, ROW_SHR4)
    DPP_ADD(S0, ROW_SHR8) DPP_ADD(S1, ROW_SHR8) DPP_ADD(S2, ROW_SHR8) DPP_ADD(S3, ROW_SHR8)

    if (c == 15) {   // rows q*4+r; store raw sums, log applied in epilogue
      smcw[t * 16 + q * 4 + 0] = S0;
      smcw[t * 16 + q * 4 + 1] = S1;
      smcw[t * 16 + q * 4 + 2] = S2;
      smcw[t * 16 + q * 4 + 3] = S3;
    }
    A = An;
  }
  __syncthreads();

  // ---- Epilogue: recurrence + smooth-min, one thread per point ----
  if (tid < PTS_PER_BLOCK) {
    float F = 0.0f;
#pragma unroll
    for (int l = 0; l < LL; ++l) {
      float wv = swv[l];
      float mc = C_GLN2 * LOG2F(smc[l * PTS_PER_BLOCK + tid]);  // gamma*ln(S)
      F = fmaf(wv, fmaxf(F, 0.0f), (1.0f - wv) * mc);
    }
    int idx = pbase + tid;
    if (idx < NPOINTS) {
      float e = EXP2F(F * C_AA);              // exp(-F/0.1)
      out[idx] = C_GLN2 * LOG2F(1.0f + e);    // 0.1 * ln(1 + e)
    }
  }
}

extern "C" void kernel_launch(void* const* d_in, const int* in_sizes, int n_in,
                              void* d_out, int out_size, void* d_ws, size_t ws_size,
                              hipStream_t stream) {
  const float* xs = (const float*)d_in[0];     // [N, D]
  const float* mus = (const float*)d_in[1];    // [L, D, K]
  const float* alphas = (const float*)d_in[2]; // [L, K]
  const float* wsv = (const float*)d_in[3];    // [L]
  float* out = (float*)d_out;
  (void)d_ws; (void)ws_size;

  const int blocks = (NPOINTS + PTS_PER_BLOCK - 1) / PTS_PER_BLOCK;  // 977
  multiinf_kernel<<<blocks, TPB, 0, stream>>>(xs, mus, alphas, wsv, out);
}